// Round 8
// baseline (468.274 us; speedup 1.0000x reference)
//
#include <hip/hip_runtime.h>
#include <float.h>

// Sparsemax attention, dense uniform pipeline v2b.
// B=2,H=16,S=2048,D=64 fp32, temperature 8.
// = round 7 structure (BROWS=16, 512 thr, split-K phase 2, 68 KB LDS,
//   2 blocks/CU) with sparsemax reverted to the round-6-PROVEN scalar-fp32
//   bisection + exact finish (bisects out the packed-fp16 Michelot).
//
// prep: K -> fp16 (ws), V -> fp16 TRANSPOSED VT[bh][64][2048] (ws).
// main (per block: 16 q-rows, 512 thr, 8 waves):
//   phase 1: raw scores = Q K^T via mfma_f32_16x16x32_f16 -> fp16 LDS
//            (XOR-swizzled [16][2048]). Wave w owns cols [w*256,(w+1)*256).
//   sparsemax: wave w owns rows {2w,2w+1}: scores unpacked to fp32 regs,
//            row max -> 12 bisection iters on g(t)=sum(max(s-t,0)) vs 8
//            -> exact finish over {s>lo} -> p=max(s-tau,0) fp16 to LDS.
//   phase 2: O = P V via MFMA, split-K across wave pairs (w&3 = col tile,
//            w>>2 = K half), 4 KB LDS reduce, epilogue *0.125.
// No atomics, no data-dependent control flow.

#define S_LEN 2048
#define DHEAD 64
#define BROWS 16
#define NWAVES 8
#define BITERS 12

typedef _Float16 f16x8 __attribute__((ext_vector_type(8)));
typedef __attribute__((ext_vector_type(4))) float f32x4;
typedef __attribute__((ext_vector_type(8))) unsigned short u16x8;

__device__ __forceinline__ unsigned short f2h(float x) {
    return __builtin_bit_cast(unsigned short, (_Float16)x);
}
__device__ __forceinline__ float h2f(unsigned short u) {
    return (float)__builtin_bit_cast(_Float16, u);
}
__device__ __forceinline__ unsigned int pk2h(float lo, float hi) {
    return (unsigned int)f2h(lo) | ((unsigned int)f2h(hi) << 16);
}
__device__ __forceinline__ f16x8 cvt8h(float4 a, float4 b) {
    union { unsigned int u[4]; f16x8 v; } r;
    r.u[0] = pk2h(a.x, a.y); r.u[1] = pk2h(a.z, a.w);
    r.u[2] = pk2h(b.x, b.y); r.u[3] = pk2h(b.z, b.w);
    return r.v;
}

// swizzled LDS ushort index; flips idx bits 3-5 by row&7 -> breaks the
// stride-4096B conflict on phase-2 A-fragment ds_read_b128.
__device__ __forceinline__ int p_idx(int row, int col) {
    return (row * S_LEN + col) ^ ((row & 7) << 3);
}

__global__ __launch_bounds__(256)
void cvt_f16_kernel(const float* __restrict__ src, uint4* __restrict__ dst, int n8) {
    int i = blockIdx.x * 256 + threadIdx.x;
    if (i >= n8) return;
    const float4* s4 = reinterpret_cast<const float4*>(src);
    float4 a = s4[2 * i], b = s4[2 * i + 1];
    uint4 o;
    o.x = pk2h(a.x, a.y); o.y = pk2h(a.z, a.w);
    o.z = pk2h(b.x, b.y); o.w = pk2h(b.z, b.w);
    dst[i] = o;
}

// V[bh][2048][64] fp32 -> VT[bh][64][2048] fp16, 64x64 tiles via LDS
__global__ __launch_bounds__(256)
void vt_kernel(const float* __restrict__ V, unsigned short* __restrict__ VT) {
    __shared__ unsigned short tile[64][72];   // +8 pad
    const int t  = threadIdx.x;
    const int bh = blockIdx.x >> 5;           // 32 s-tiles per bh
    const int s0 = (blockIdx.x & 31) * 64;
    const float* Vb = V + ((size_t)bh * S_LEN + s0) * DHEAD;
    const int r = t >> 2, q = t & 3;
    #pragma unroll
    for (int j = 0; j < 4; ++j) {
        float4 v4 = *reinterpret_cast<const float4*>(Vb + (size_t)r * DHEAD + q * 16 + j * 4);
        tile[r][q * 16 + j * 4 + 0] = f2h(v4.x);
        tile[r][q * 16 + j * 4 + 1] = f2h(v4.y);
        tile[r][q * 16 + j * 4 + 2] = f2h(v4.z);
        tile[r][q * 16 + j * 4 + 3] = f2h(v4.w);
    }
    __syncthreads();
    const int d = t >> 2;
    union { unsigned short s[16]; u16x8 v[2]; } o;
    #pragma unroll
    for (int i = 0; i < 16; ++i) o.s[i] = tile[q * 16 + i][d];
    u16x8* dst = reinterpret_cast<u16x8*>(VT + ((size_t)bh * DHEAD + d) * S_LEN + s0 + q * 16);
    dst[0] = o.v[0];
    dst[1] = o.v[1];
}

__global__ __launch_bounds__(512)
void spx_main(const float* __restrict__ Q,
              const unsigned short* __restrict__ Kh,
              const unsigned short* __restrict__ VT,
              float* __restrict__ O)
{
    __shared__ unsigned short s_p[BROWS * S_LEN];   // 64 KB, swizzled
    __shared__ float s_red[4][64][4];               // 4 KB phase-2 reduce

    const int t  = threadIdx.x;
    const int w  = t >> 6;
    const int l  = t & 63;
    const int lm = l & 15;
    const int lk = l >> 4;

    int bid = blockIdx.x;
    if (((int)gridDim.x & 7) == 0)
        bid = (bid & 7) * ((int)gridDim.x >> 3) + (bid >> 3);   // XCD swizzle
    const int nrb  = S_LEN / BROWS;                  // 128
    const int bh   = bid / nrb;
    const int row0 = (bid % nrb) * BROWS;

    const size_t bhoff = (size_t)bh * S_LEN * DHEAD;
    const float* Qf = Q + bhoff;
    const unsigned short* KhB = Kh + bhoff;
    const unsigned short* VTb = VT + bhoff;
    float* Of = O + bhoff;

    // ---- A fragments: Q[row0+lm][kp*32 + lk*8 + 0..7] (inline fp32->fp16) ----
    f16x8 afrag[2];
    #pragma unroll
    for (int kp = 0; kp < 2; ++kp) {
        const float* qp = Qf + (size_t)(row0 + lm) * DHEAD + kp * 32 + lk * 8;
        afrag[kp] = cvt8h(*reinterpret_cast<const float4*>(qp),
                          *reinterpret_cast<const float4*>(qp + 4));
    }

    // ---- phase 1: raw scores -> fp16 LDS ----
    const int col0 = w * (S_LEN / NWAVES);           // 256 cols per wave
    #pragma unroll 4
    for (int ct = 0; ct < 16; ++ct) {
        const int kc = col0 + ct * 16 + lm;
        const unsigned short* kp8 = KhB + (size_t)kc * DHEAD;
        f16x8 b0 = *reinterpret_cast<const f16x8*>(kp8 + lk * 8);
        f16x8 b1 = *reinterpret_cast<const f16x8*>(kp8 + 32 + lk * 8);
        f32x4 a0 = (f32x4){0.f, 0.f, 0.f, 0.f};
        a0 = __builtin_amdgcn_mfma_f32_16x16x32_f16(afrag[0], b0, a0, 0, 0, 0);
        a0 = __builtin_amdgcn_mfma_f32_16x16x32_f16(afrag[1], b1, a0, 0, 0, 0);
        #pragma unroll
        for (int e = 0; e < 4; ++e)
            s_p[p_idx(lk * 4 + e, kc)] = f2h(a0[e]);
    }
    __syncthreads();

    // ---- sparsemax: wave w owns rows {2w, 2w+1} (round-6 proven path) ----
    {
        const int r0 = w * 2;
        float sc[2][32];
        #pragma unroll
        for (int r = 0; r < 2; ++r)
            #pragma unroll
            for (int c = 0; c < 4; ++c) {
                u16x8 v = *reinterpret_cast<const u16x8*>(&s_p[p_idx(r0 + r, c * 512 + l * 8)]);
                #pragma unroll
                for (int e = 0; e < 8; ++e) sc[r][c * 8 + e] = h2f(v[e]);
            }

        // row max (raw units)
        float mx[2];
        #pragma unroll
        for (int r = 0; r < 2; ++r) {
            float m = sc[r][0];
            #pragma unroll
            for (int i = 1; i < 32; ++i) m = fmaxf(m, sc[r][i]);
            mx[r] = m;
        }
        #pragma unroll
        for (int o = 1; o < 64; o <<= 1)
            #pragma unroll
            for (int r = 0; r < 2; ++r) mx[r] = fmaxf(mx[r], __shfl_xor(mx[r], o));

        // bisection on g(t) = sum(max(s-t,0)) vs 8 (raw units: tau_raw)
        float lo[2], hi[2];
        #pragma unroll
        for (int r = 0; r < 2; ++r) { lo[r] = mx[r] - 8.f; hi[r] = mx[r]; }
        for (int it = 0; it < BITERS; ++it) {
            float g[2], tm[2];
            #pragma unroll
            for (int r = 0; r < 2; ++r) {
                tm[r] = 0.5f * (lo[r] + hi[r]);
                float s = 0.f;
                #pragma unroll
                for (int i = 0; i < 32; ++i) s += fmaxf(sc[r][i] - tm[r], 0.f);
                g[r] = s;
            }
            #pragma unroll
            for (int o = 1; o < 64; o <<= 1)
                #pragma unroll
                for (int r = 0; r < 2; ++r) g[r] += __shfl_xor(g[r], o);
            #pragma unroll
            for (int r = 0; r < 2; ++r) {
                if (g[r] >= 8.f) lo[r] = tm[r]; else hi[r] = tm[r];
            }
        }
        // exact finish over {s > lo}: tau = (sum - 8)/cnt
        float sm[2], cn[2];
        #pragma unroll
        for (int r = 0; r < 2; ++r) {
            float s = 0.f, c = 0.f;
            #pragma unroll
            for (int i = 0; i < 32; ++i) {
                const bool in = sc[r][i] > lo[r];
                s += in ? sc[r][i] : 0.f;
                c += in ? 1.f : 0.f;
            }
            sm[r] = s; cn[r] = c;
        }
        #pragma unroll
        for (int o = 1; o < 64; o <<= 1)
            #pragma unroll
            for (int r = 0; r < 2; ++r) {
                sm[r] += __shfl_xor(sm[r], o);
                cn[r] += __shfl_xor(cn[r], o);
            }
        float tau[2];
        #pragma unroll
        for (int r = 0; r < 2; ++r) tau[r] = (sm[r] - 8.f) / cn[r];

        // p = max(s - tau, 0) -> fp16 back into LDS (same swizzled slots)
        #pragma unroll
        for (int r = 0; r < 2; ++r) {
            #pragma unroll
            for (int c = 0; c < 4; ++c) {
                union { unsigned int u[4]; u16x8 v; } pw;
                #pragma unroll
                for (int e = 0; e < 4; ++e) {
                    float p0 = fmaxf(sc[r][c * 8 + 2 * e]     - tau[r], 0.f);
                    float p1 = fmaxf(sc[r][c * 8 + 2 * e + 1] - tau[r], 0.f);
                    pw.u[e] = pk2h(p0, p1);
                }
                *reinterpret_cast<u16x8*>(&s_p[p_idx(r0 + r, c * 512 + l * 8)]) = pw.v;
            }
        }
    }
    __syncthreads();

    // ---- phase 2: O = P V, split-K: wave -> (col tile w&3, K half w>>2) ----
    {
        const int nt = w & 3;
        const int kh = w >> 2;
        const int kbase = kh * (S_LEN / 2);
        const unsigned short* vrow = VTb + (size_t)(nt * 16 + lm) * S_LEN + kbase;
        f32x4 acc = (f32x4){0.f, 0.f, 0.f, 0.f};
        #pragma unroll 8
        for (int ks = 0; ks < S_LEN / 64; ++ks) {
            f16x8 pa = *reinterpret_cast<const f16x8*>(
                &s_p[p_idx(lm, kbase + ks * 32 + lk * 8)]);
            f16x8 pb = *reinterpret_cast<const f16x8*>(vrow + ks * 32 + lk * 8);
            acc = __builtin_amdgcn_mfma_f32_16x16x32_f16(pa, pb, acc, 0, 0, 0);
        }
        if (w >= 4) {
            #pragma unroll
            for (int e = 0; e < 4; ++e) s_red[nt][l][e] = acc[e];
        }
        __syncthreads();
        if (w < 4) {
            #pragma unroll
            for (int e = 0; e < 4; ++e) {
                const float o = (acc[e] + s_red[nt][l][e]) * 0.125f;
                Of[(size_t)(row0 + lk * 4 + e) * DHEAD + nt * 16 + lm] = o;
            }
        }
    }
}

extern "C" void kernel_launch(void* const* d_in, const int* in_sizes, int n_in,
                              void* d_out, int out_size, void* d_ws, size_t ws_size,
                              hipStream_t stream) {
    const float* q = (const float*)d_in[0];
    const float* k = (const float*)d_in[1];
    const float* v = (const float*)d_in[2];
    float* out = (float*)d_out;

    const int nElem = in_sizes[0];                    // B*H*S*D
    const int BH    = nElem / (S_LEN * DHEAD);

    unsigned short* kh = (unsigned short*)d_ws;
    unsigned short* vt = kh + nElem;

    const int n8 = nElem / 8;
    cvt_f16_kernel<<<(n8 + 255) / 256, 256, 0, stream>>>(k, (uint4*)kh, n8);
    vt_kernel<<<BH * (S_LEN / 64), 256, 0, stream>>>(v, vt);
    spx_main<<<BH * (S_LEN / BROWS), 512, 0, stream>>>(q, kh, vt, out);
}

// Round 9
// 338.999 us; speedup vs baseline: 1.3813x; 1.3813x over previous
//
#include <hip/hip_runtime.h>
#include <float.h>

// Sparsemax attention v3: swapped-operand MFMA, scores in registers.
// B=2,H=16,S=2048,D=64 fp32, temperature 8.
//
// prep: K -> fp16 (ws), V -> fp16 TRANSPOSED VT[bh][64][2048] (ws).
// main (block = 16 q-rows, 512 thr, 8 waves, ~36 KB LDS, 2 blocks/CU):
//   QK^T swapped: acc = mfma(A=K_tile, B=Q^T_frag) -> lane (lm,lk) holds
//     S[qrow=lm][kcol = col0 + ct*16 + lk*4 + e]; wave w owns kcol slab
//     [w*256,(w+1)*256). Scores NEVER leave registers (fp32).
//   row stats: q-row lives in the lm lane dim -> shfl_xor(16,32) + per-wave
//     LDS partials [8][16] + barrier (rows fully parallel).
//   Michelot (fixed 12 iters, double-buffered LDS partials, 1 barrier/iter):
//     t0 = rowmax-8; t' = (Sum_{s>t} s - 8)/cnt; exact tau at fixpoint.
//   PV: per 32-col chunk: p = max(s-tv,0) packed fp16 (2 cts), shuffled into
//     B-fragments (8 bpermutes + select), A = VT rows (contiguous fp16);
//     split-K across waves -> staged LDS reduce [8][16][65] -> O * 0.125.
// No atomics, no data-dependent control flow (fixed iteration counts).

#define S_LEN 2048
#define DHEAD 64
#define BROWS 16
#define NWAVES 8
#define MITERS 12

typedef _Float16 f16x8 __attribute__((ext_vector_type(8)));
typedef __attribute__((ext_vector_type(4))) float f32x4;
typedef __attribute__((ext_vector_type(8))) unsigned short u16x8;

__device__ __forceinline__ unsigned short f2h(float x) {
    return __builtin_bit_cast(unsigned short, (_Float16)x);
}
__device__ __forceinline__ unsigned int pk2h(float lo, float hi) {
    return (unsigned int)f2h(lo) | ((unsigned int)f2h(hi) << 16);
}
__device__ __forceinline__ f16x8 cvt8h(float4 a, float4 b) {
    union { unsigned int u[4]; f16x8 v; } r;
    r.u[0] = pk2h(a.x, a.y); r.u[1] = pk2h(a.z, a.w);
    r.u[2] = pk2h(b.x, b.y); r.u[3] = pk2h(b.z, b.w);
    return r.v;
}

__global__ __launch_bounds__(256)
void cvt_f16_kernel(const float* __restrict__ src, uint4* __restrict__ dst, int n8) {
    int i = blockIdx.x * 256 + threadIdx.x;
    if (i >= n8) return;
    const float4* s4 = reinterpret_cast<const float4*>(src);
    float4 a = s4[2 * i], b = s4[2 * i + 1];
    uint4 o;
    o.x = pk2h(a.x, a.y); o.y = pk2h(a.z, a.w);
    o.z = pk2h(b.x, b.y); o.w = pk2h(b.z, b.w);
    dst[i] = o;
}

// V[bh][2048][64] fp32 -> VT[bh][64][2048] fp16, 64x64 tiles via LDS
__global__ __launch_bounds__(256)
void vt_kernel(const float* __restrict__ V, unsigned short* __restrict__ VT) {
    __shared__ unsigned short tile[64][72];   // +8 pad
    const int t  = threadIdx.x;
    const int bh = blockIdx.x >> 5;           // 32 s-tiles per bh
    const int s0 = (blockIdx.x & 31) * 64;
    const float* Vb = V + ((size_t)bh * S_LEN + s0) * DHEAD;
    const int r = t >> 2, q = t & 3;
    #pragma unroll
    for (int j = 0; j < 4; ++j) {
        float4 v4 = *reinterpret_cast<const float4*>(Vb + (size_t)r * DHEAD + q * 16 + j * 4);
        tile[r][q * 16 + j * 4 + 0] = f2h(v4.x);
        tile[r][q * 16 + j * 4 + 1] = f2h(v4.y);
        tile[r][q * 16 + j * 4 + 2] = f2h(v4.z);
        tile[r][q * 16 + j * 4 + 3] = f2h(v4.w);
    }
    __syncthreads();
    const int d = t >> 2;
    union { unsigned short s[16]; u16x8 v[2]; } o;
    #pragma unroll
    for (int i = 0; i < 16; ++i) o.s[i] = tile[q * 16 + i][d];
    u16x8* dst = reinterpret_cast<u16x8*>(VT + ((size_t)bh * DHEAD + d) * S_LEN + s0 + q * 16);
    dst[0] = o.v[0];
    dst[1] = o.v[1];
}

__global__ __launch_bounds__(512, 4)
void spx_main(const float* __restrict__ Q,
              const unsigned short* __restrict__ Kh,
              const unsigned short* __restrict__ VT,
              float* __restrict__ O)
{
    __shared__ float s_pm[NWAVES][BROWS];            // row-max partials
    __shared__ float s_ps[2][NWAVES][BROWS];         // Michelot sum partials
    __shared__ float s_pc[2][NWAVES][BROWS];         // Michelot cnt partials
    __shared__ float s_red[NWAVES][BROWS][65];       // PV split-K reduce (33 KB)

    const int t  = threadIdx.x;
    const int w  = t >> 6;
    const int l  = t & 63;
    const int lm = l & 15;
    const int lk = l >> 4;

    int bid = blockIdx.x;
    if (((int)gridDim.x & 7) == 0)
        bid = (bid & 7) * ((int)gridDim.x >> 3) + (bid >> 3);   // XCD swizzle
    const int nrb  = S_LEN / BROWS;                  // 128
    const int bh   = bid / nrb;
    const int row0 = (bid % nrb) * BROWS;

    const size_t bhoff = (size_t)bh * S_LEN * DHEAD;
    const float* Qf = Q + bhoff;
    const unsigned short* KhB = Kh + bhoff;
    const unsigned short* VTb = VT + bhoff;
    float* Of = O + bhoff;

    // ---- Q^T B-fragments: lane (lm,lk) = Q[row0+lm][kp*32 + lk*8 + j] ----
    f16x8 qfrag[2];
    #pragma unroll
    for (int kp = 0; kp < 2; ++kp) {
        const float* qp = Qf + (size_t)(row0 + lm) * DHEAD + kp * 32 + lk * 8;
        qfrag[kp] = cvt8h(*reinterpret_cast<const float4*>(qp),
                          *reinterpret_cast<const float4*>(qp + 4));
    }

    // ---- swapped QK^T: acc[ct][e] = S[qrow=lm][col0 + ct*16 + lk*4 + e] ----
    const int col0 = w * (S_LEN / NWAVES);           // 256-wide slab
    f32x4 acc[16];
    #pragma unroll
    for (int ct = 0; ct < 16; ++ct) acc[ct] = (f32x4){0.f, 0.f, 0.f, 0.f};

    #pragma unroll
    for (int ct = 0; ct < 16; ++ct) {
        const unsigned short* kp8 = KhB + (size_t)(col0 + ct * 16 + lm) * DHEAD;
        f16x8 k0 = *reinterpret_cast<const f16x8*>(kp8 + lk * 8);
        f16x8 k1 = *reinterpret_cast<const f16x8*>(kp8 + 32 + lk * 8);
        acc[ct] = __builtin_amdgcn_mfma_f32_16x16x32_f16(k0, qfrag[0], acc[ct], 0, 0, 0);
        acc[ct] = __builtin_amdgcn_mfma_f32_16x16x32_f16(k1, qfrag[1], acc[ct], 0, 0, 0);
    }

    // ---- row max (row = lm): lane-local over 64 vals, shfl over lk, LDS ----
    float mx;
    {
        float m = acc[0][0];
        #pragma unroll
        for (int ct = 0; ct < 16; ++ct)
            #pragma unroll
            for (int e = 0; e < 4; ++e) m = fmaxf(m, acc[ct][e]);
        m = fmaxf(m, __shfl_xor(m, 16));
        m = fmaxf(m, __shfl_xor(m, 32));
        if (lk == 0) s_pm[w][lm] = m;
    }
    __syncthreads();
    {
        float m = s_pm[0][lm];
        #pragma unroll
        for (int ww = 1; ww < NWAVES; ++ww) m = fmaxf(m, s_pm[ww][lm]);
        mx = m;
    }

    // ---- Michelot, fixed 12 iters (exact tau at fixpoint; converges <=~7
    //      for Gaussian scores; extra iters are idempotent) ----
    float tv = mx - 8.f;
    for (int it = 0; it < MITERS; ++it) {
        float s = 0.f, c = 0.f;
        #pragma unroll
        for (int ct = 0; ct < 16; ++ct)
            #pragma unroll
            for (int e = 0; e < 4; ++e) {
                const float v = acc[ct][e];
                const bool in = v > tv;
                s += in ? v : 0.f;
                c += in ? 1.f : 0.f;
            }
        s += __shfl_xor(s, 16); s += __shfl_xor(s, 32);
        c += __shfl_xor(c, 16); c += __shfl_xor(c, 32);
        const int slot = it & 1;
        if (lk == 0) { s_ps[slot][w][lm] = s; s_pc[slot][w][lm] = c; }
        __syncthreads();
        float S = 0.f, C = 0.f;
        #pragma unroll
        for (int ww = 0; ww < NWAVES; ++ww) {
            S += s_ps[slot][ww][lm];
            C += s_pc[slot][ww][lm];
        }
        tv = (S - 8.f) / C;
    }

    // ---- PV: per 32-col chunk, pack p -> fp16, shuffle into B-frag, MFMA ----
    f32x4 pv[4];
    #pragma unroll
    for (int d0 = 0; d0 < 4; ++d0) pv[d0] = (f32x4){0.f, 0.f, 0.f, 0.f};

    const int srcA = lm + 32 * (lk & 1);     // lane holding kcols (lk&1)*8+0..3
    const int srcB = srcA + 16;              // +4..7
    const bool hiCt = (lk >> 1) != 0;        // this lane's chunk-half: ct=2ch+1?

    #pragma unroll
    for (int ch = 0; ch < 8; ++ch) {
        // pack p = max(s - tv, 0) for cts 2ch, 2ch+1 (all lanes pack both)
        const unsigned int pA0 = pk2h(fmaxf(acc[2 * ch][0] - tv, 0.f),
                                      fmaxf(acc[2 * ch][1] - tv, 0.f));
        const unsigned int pA1 = pk2h(fmaxf(acc[2 * ch][2] - tv, 0.f),
                                      fmaxf(acc[2 * ch][3] - tv, 0.f));
        const unsigned int pB0 = pk2h(fmaxf(acc[2 * ch + 1][0] - tv, 0.f),
                                      fmaxf(acc[2 * ch + 1][1] - tv, 0.f));
        const unsigned int pB1 = pk2h(fmaxf(acc[2 * ch + 1][2] - tv, 0.f),
                                      fmaxf(acc[2 * ch + 1][3] - tv, 0.f));
        // gather this lane's B-frag words: k = ch*32 + lk*8 + j, j=0..7
        const unsigned int xA0 = (unsigned int)__shfl((int)pA0, srcA);
        const unsigned int xB0 = (unsigned int)__shfl((int)pB0, srcA);
        const unsigned int xA1 = (unsigned int)__shfl((int)pA1, srcA);
        const unsigned int xB1 = (unsigned int)__shfl((int)pB1, srcA);
        const unsigned int yA0 = (unsigned int)__shfl((int)pA0, srcB);
        const unsigned int yB0 = (unsigned int)__shfl((int)pB0, srcB);
        const unsigned int yA1 = (unsigned int)__shfl((int)pA1, srcB);
        const unsigned int yB1 = (unsigned int)__shfl((int)pB1, srcB);
        union { unsigned int u[4]; f16x8 v; } pf;
        pf.u[0] = hiCt ? xB0 : xA0;   // j 0..1
        pf.u[1] = hiCt ? xB1 : xA1;   // j 2..3
        pf.u[2] = hiCt ? yB0 : yA0;   // j 4..5
        pf.u[3] = hiCt ? yB1 : yA1;   // j 6..7
        // A = VT rows (dim-major), k = global kcol = col0 + ch*32 + lk*8
        #pragma unroll
        for (int d0 = 0; d0 < 4; ++d0) {
            const unsigned short* vp = VTb + (size_t)(d0 * 16 + lm) * S_LEN
                                           + col0 + ch * 32 + lk * 8;
            f16x8 vfrag = *reinterpret_cast<const f16x8*>(vp);
            pv[d0] = __builtin_amdgcn_mfma_f32_16x16x32_f16(vfrag, pf.v, pv[d0], 0, 0, 0);
        }
    }

    // ---- split-K reduce: pv[d0][e] = O^T[dim=d0*16+lk*4+e][qrow=lm] ----
    #pragma unroll
    for (int d0 = 0; d0 < 4; ++d0)
        #pragma unroll
        for (int e = 0; e < 4; ++e)
            s_red[w][lm][d0 * 16 + lk * 4 + e] = pv[d0][e];
    __syncthreads();

    #pragma unroll
    for (int rep = 0; rep < 2; ++rep) {
        const int idx = t + rep * 512;
        const int qr  = idx >> 6;
        const int d   = idx & 63;
        float o = 0.f;
        #pragma unroll
        for (int ww = 0; ww < NWAVES; ++ww) o += s_red[ww][qr][d];
        Of[(size_t)(row0 + qr) * DHEAD + d] = o * 0.125f;
    }
}

extern "C" void kernel_launch(void* const* d_in, const int* in_sizes, int n_in,
                              void* d_out, int out_size, void* d_ws, size_t ws_size,
                              hipStream_t stream) {
    const float* q = (const float*)d_in[0];
    const float* k = (const float*)d_in[1];
    const float* v = (const float*)d_in[2];
    float* out = (float*)d_out;

    const int nElem = in_sizes[0];                    // B*H*S*D
    const int BH    = nElem / (S_LEN * DHEAD);

    unsigned short* kh = (unsigned short*)d_ws;
    unsigned short* vt = kh + nElem;

    const int n8 = nElem / 8;
    cvt_f16_kernel<<<(n8 + 255) / 256, 256, 0, stream>>>(k, (uint4*)kh, n8);
    vt_kernel<<<BH * (S_LEN / 64), 256, 0, stream>>>(v, vt);
    spx_main<<<BH * (S_LEN / BROWS), 512, 0, stream>>>(q, kh, vt, out);
}

// Round 10
// 304.774 us; speedup vs baseline: 1.5365x; 1.1123x over previous
//
#include <hip/hip_runtime.h>
#include <float.h>

// Sparsemax attention v4: swapped-operand MFMA + candidate-list Michelot.
// B=2,H=16,S=2048,D=64 fp32, temperature 8.
//
// = round-9 architecture (scores in registers, swapped QK^T, shuffle-transpose
//   PV, split-K reduce) with the fixed-12 full-scan Michelot replaced by:
//   - collect {s > rowmax-8} (superset of support) into per-row LDS value
//     lists at DETERMINISTIC slots (lane (w,lm,lk) owns 8 slots; no atomics);
//   - per-lane cap overflow -> block-uniform flag -> round-9 full-scan
//     fallback (correct for any data; never hit for Gaussian);
//   - wave w runs in-wave Michelot for rows {2w,2w+1} on the <=256-entry
//     lists: ~4 iters, early break, zero barriers in the loop.

#define S_LEN 2048
#define DHEAD 64
#define BROWS 16
#define NWAVES 8
#define FB_ITERS 12
#define LCAP 8

typedef _Float16 f16x8 __attribute__((ext_vector_type(8)));
typedef __attribute__((ext_vector_type(4))) float f32x4;
typedef __attribute__((ext_vector_type(8))) unsigned short u16x8;

__device__ __forceinline__ unsigned short f2h(float x) {
    return __builtin_bit_cast(unsigned short, (_Float16)x);
}
__device__ __forceinline__ unsigned int pk2h(float lo, float hi) {
    return (unsigned int)f2h(lo) | ((unsigned int)f2h(hi) << 16);
}
__device__ __forceinline__ f16x8 cvt8h(float4 a, float4 b) {
    union { unsigned int u[4]; f16x8 v; } r;
    r.u[0] = pk2h(a.x, a.y); r.u[1] = pk2h(a.z, a.w);
    r.u[2] = pk2h(b.x, b.y); r.u[3] = pk2h(b.z, b.w);
    return r.v;
}

__global__ __launch_bounds__(256)
void cvt_f16_kernel(const float* __restrict__ src, uint4* __restrict__ dst, int n8) {
    int i = blockIdx.x * 256 + threadIdx.x;
    if (i >= n8) return;
    const float4* s4 = reinterpret_cast<const float4*>(src);
    float4 a = s4[2 * i], b = s4[2 * i + 1];
    uint4 o;
    o.x = pk2h(a.x, a.y); o.y = pk2h(a.z, a.w);
    o.z = pk2h(b.x, b.y); o.w = pk2h(b.z, b.w);
    dst[i] = o;
}

// V[bh][2048][64] fp32 -> VT[bh][64][2048] fp16, 64x64 tiles via LDS
__global__ __launch_bounds__(256)
void vt_kernel(const float* __restrict__ V, unsigned short* __restrict__ VT) {
    __shared__ unsigned short tile[64][72];   // +8 pad
    const int t  = threadIdx.x;
    const int bh = blockIdx.x >> 5;           // 32 s-tiles per bh
    const int s0 = (blockIdx.x & 31) * 64;
    const float* Vb = V + ((size_t)bh * S_LEN + s0) * DHEAD;
    const int r = t >> 2, q = t & 3;
    #pragma unroll
    for (int j = 0; j < 4; ++j) {
        float4 v4 = *reinterpret_cast<const float4*>(Vb + (size_t)r * DHEAD + q * 16 + j * 4);
        tile[r][q * 16 + j * 4 + 0] = f2h(v4.x);
        tile[r][q * 16 + j * 4 + 1] = f2h(v4.y);
        tile[r][q * 16 + j * 4 + 2] = f2h(v4.z);
        tile[r][q * 16 + j * 4 + 3] = f2h(v4.w);
    }
    __syncthreads();
    const int d = t >> 2;
    union { unsigned short s[16]; u16x8 v[2]; } o;
    #pragma unroll
    for (int i = 0; i < 16; ++i) o.s[i] = tile[q * 16 + i][d];
    u16x8* dst = reinterpret_cast<u16x8*>(VT + ((size_t)bh * DHEAD + d) * S_LEN + s0 + q * 16);
    dst[0] = o.v[0];
    dst[1] = o.v[1];
}

__global__ __launch_bounds__(512, 4)
void spx_main(const float* __restrict__ Q,
              const unsigned short* __restrict__ Kh,
              const unsigned short* __restrict__ VT,
              float* __restrict__ O)
{
    __shared__ float s_pm[NWAVES][BROWS];            // row-max partials
    __shared__ float s_rm[BROWS];                    // combined row max
    __shared__ float s_ps[2][NWAVES][BROWS];         // fallback sum partials
    __shared__ float s_pc[2][NWAVES][BROWS];         // fallback cnt partials
    __shared__ float s_lv[BROWS][256];               // candidate lists (16 KB)
    __shared__ int   s_lc[BROWS][NWAVES][4];         // per-(row,w,lk) counts
    __shared__ float s_tau[BROWS];
    __shared__ int   s_ovf;
    __shared__ float s_red[NWAVES][BROWS][65];       // PV split-K reduce (33 KB)

    const int t  = threadIdx.x;
    const int w  = t >> 6;
    const int l  = t & 63;
    const int lm = l & 15;
    const int lk = l >> 4;

    int bid = blockIdx.x;
    if (((int)gridDim.x & 7) == 0)
        bid = (bid & 7) * ((int)gridDim.x >> 3) + (bid >> 3);   // XCD swizzle
    const int nrb  = S_LEN / BROWS;                  // 128
    const int bh   = bid / nrb;
    const int row0 = (bid % nrb) * BROWS;

    const size_t bhoff = (size_t)bh * S_LEN * DHEAD;
    const float* Qf = Q + bhoff;
    const unsigned short* KhB = Kh + bhoff;
    const unsigned short* VTb = VT + bhoff;
    float* Of = O + bhoff;

    if (t == 0) s_ovf = 0;

    // ---- Q^T B-fragments: lane (lm,lk) = Q[row0+lm][kp*32 + lk*8 + j] ----
    f16x8 qfrag[2];
    #pragma unroll
    for (int kp = 0; kp < 2; ++kp) {
        const float* qp = Qf + (size_t)(row0 + lm) * DHEAD + kp * 32 + lk * 8;
        qfrag[kp] = cvt8h(*reinterpret_cast<const float4*>(qp),
                          *reinterpret_cast<const float4*>(qp + 4));
    }

    // ---- swapped QK^T: acc[ct][e] = S[qrow=lm][col0 + ct*16 + lk*4 + e] ----
    const int col0 = w * (S_LEN / NWAVES);           // 256-wide slab
    f32x4 acc[16];
    #pragma unroll
    for (int ct = 0; ct < 16; ++ct) acc[ct] = (f32x4){0.f, 0.f, 0.f, 0.f};

    #pragma unroll
    for (int ct = 0; ct < 16; ++ct) {
        const unsigned short* kp8 = KhB + (size_t)(col0 + ct * 16 + lm) * DHEAD;
        f16x8 k0 = *reinterpret_cast<const f16x8*>(kp8 + lk * 8);
        f16x8 k1 = *reinterpret_cast<const f16x8*>(kp8 + 32 + lk * 8);
        acc[ct] = __builtin_amdgcn_mfma_f32_16x16x32_f16(k0, qfrag[0], acc[ct], 0, 0, 0);
        acc[ct] = __builtin_amdgcn_mfma_f32_16x16x32_f16(k1, qfrag[1], acc[ct], 0, 0, 0);
    }

    // ---- row max (row = lm) ----
    {
        float m = acc[0][0];
        #pragma unroll
        for (int ct = 0; ct < 16; ++ct)
            #pragma unroll
            for (int e = 0; e < 4; ++e) m = fmaxf(m, acc[ct][e]);
        m = fmaxf(m, __shfl_xor(m, 16));
        m = fmaxf(m, __shfl_xor(m, 32));
        if (lk == 0) s_pm[w][lm] = m;
    }
    __syncthreads();
    float mx;
    {
        float m = s_pm[0][lm];
        #pragma unroll
        for (int ww = 1; ww < NWAVES; ++ww) m = fmaxf(m, s_pm[ww][lm]);
        mx = m;
    }
    if (w == 0 && lk == 0) s_rm[lm] = mx;

    // ---- candidate collection: {s > mx-8} -> deterministic LDS slots ----
    {
        const float thr0 = mx - 8.f;
        const int base = w * 32 + lk * 8;
        int own = 0;
        bool of = false;
        #pragma unroll
        for (int ct = 0; ct < 16; ++ct)
            #pragma unroll
            for (int e = 0; e < 4; ++e) {
                const float v = acc[ct][e];
                if (v > thr0) {
                    if (own < LCAP) { s_lv[lm][base + own] = v; ++own; }
                    else of = true;
                }
            }
        s_lc[lm][w][lk] = own;
        if (of) atomicOr(&s_ovf, 1);
    }
    __syncthreads();

    float tauF;
    if (s_ovf == 0) {
        // ---- in-wave list Michelot: wave w owns rows {2w, 2w+1} ----
        const int r0 = w * 2;
        float cv[8];
        #pragma unroll
        for (int q = 0; q < 8; ++q) {
            const int row  = r0 + (q >> 2);
            const int slot = (q & 3) * 64 + l;
            const int cnt  = s_lc[row][slot >> 5][(slot >> 3) & 3];
            const float v  = s_lv[row][slot];
            cv[q] = ((slot & 7) < cnt) ? v : -FLT_MAX;
        }
        float tv0 = s_rm[r0] - 8.f;
        float tv1 = s_rm[r0 + 1] - 8.f;
        int c0p = -1, c1p = -1;
        for (int it = 0; it < 16; ++it) {
            float s0 = 0.f, c0 = 0.f, s1 = 0.f, c1 = 0.f;
            #pragma unroll
            for (int q = 0; q < 4; ++q) {
                const float v = cv[q]; const bool in = v > tv0;
                s0 += in ? v : 0.f;  c0 += in ? 1.f : 0.f;
            }
            #pragma unroll
            for (int q = 4; q < 8; ++q) {
                const float v = cv[q]; const bool in = v > tv1;
                s1 += in ? v : 0.f;  c1 += in ? 1.f : 0.f;
            }
            #pragma unroll
            for (int o = 1; o < 64; o <<= 1) {
                s0 += __shfl_xor(s0, o); c0 += __shfl_xor(c0, o);
                s1 += __shfl_xor(s1, o); c1 += __shfl_xor(c1, o);
            }
            tv0 = (s0 - 8.f) / c0;
            tv1 = (s1 - 8.f) / c1;
            const int C0 = (int)c0, C1 = (int)c1;
            if (C0 == c0p && C1 == c1p) break;   // fixpoint: exact tau
            c0p = C0; c1p = C1;
        }
        if (l == 0) { s_tau[r0] = tv0; s_tau[r0 + 1] = tv1; }
        __syncthreads();
        tauF = s_tau[lm];
    } else {
        // ---- fallback: block-wide full-scan Michelot (round-9 proven) ----
        float tv = mx - 8.f;
        for (int it = 0; it < FB_ITERS; ++it) {
            float s = 0.f, c = 0.f;
            #pragma unroll
            for (int ct = 0; ct < 16; ++ct)
                #pragma unroll
                for (int e = 0; e < 4; ++e) {
                    const float v = acc[ct][e];
                    const bool in = v > tv;
                    s += in ? v : 0.f;
                    c += in ? 1.f : 0.f;
                }
            s += __shfl_xor(s, 16); s += __shfl_xor(s, 32);
            c += __shfl_xor(c, 16); c += __shfl_xor(c, 32);
            const int slot = it & 1;
            if (lk == 0) { s_ps[slot][w][lm] = s; s_pc[slot][w][lm] = c; }
            __syncthreads();
            float S = 0.f, C = 0.f;
            #pragma unroll
            for (int ww = 0; ww < NWAVES; ++ww) {
                S += s_ps[slot][ww][lm];
                C += s_pc[slot][ww][lm];
            }
            tv = (S - 8.f) / C;
        }
        tauF = tv;
    }

    // ---- PV: per 32-col chunk, pack p -> fp16, shuffle into B-frag, MFMA ----
    f32x4 pv[4];
    #pragma unroll
    for (int d0 = 0; d0 < 4; ++d0) pv[d0] = (f32x4){0.f, 0.f, 0.f, 0.f};

    const int srcA = lm + 32 * (lk & 1);     // lane holding kcols (lk&1)*8+0..3
    const int srcB = srcA + 16;              // +4..7
    const bool hiCt = (lk >> 1) != 0;        // this lane's chunk-half: ct=2ch+1?

    #pragma unroll
    for (int ch = 0; ch < 8; ++ch) {
        const unsigned int pA0 = pk2h(fmaxf(acc[2 * ch][0] - tauF, 0.f),
                                      fmaxf(acc[2 * ch][1] - tauF, 0.f));
        const unsigned int pA1 = pk2h(fmaxf(acc[2 * ch][2] - tauF, 0.f),
                                      fmaxf(acc[2 * ch][3] - tauF, 0.f));
        const unsigned int pB0 = pk2h(fmaxf(acc[2 * ch + 1][0] - tauF, 0.f),
                                      fmaxf(acc[2 * ch + 1][1] - tauF, 0.f));
        const unsigned int pB1 = pk2h(fmaxf(acc[2 * ch + 1][2] - tauF, 0.f),
                                      fmaxf(acc[2 * ch + 1][3] - tauF, 0.f));
        const unsigned int xA0 = (unsigned int)__shfl((int)pA0, srcA);
        const unsigned int xB0 = (unsigned int)__shfl((int)pB0, srcA);
        const unsigned int xA1 = (unsigned int)__shfl((int)pA1, srcA);
        const unsigned int xB1 = (unsigned int)__shfl((int)pB1, srcA);
        const unsigned int yA0 = (unsigned int)__shfl((int)pA0, srcB);
        const unsigned int yB0 = (unsigned int)__shfl((int)pB0, srcB);
        const unsigned int yA1 = (unsigned int)__shfl((int)pA1, srcB);
        const unsigned int yB1 = (unsigned int)__shfl((int)pB1, srcB);
        union { unsigned int u[4]; f16x8 v; } pf;
        pf.u[0] = hiCt ? xB0 : xA0;
        pf.u[1] = hiCt ? xB1 : xA1;
        pf.u[2] = hiCt ? yB0 : yA0;
        pf.u[3] = hiCt ? yB1 : yA1;
        #pragma unroll
        for (int d0 = 0; d0 < 4; ++d0) {
            const unsigned short* vp = VTb + (size_t)(d0 * 16 + lm) * S_LEN
                                           + col0 + ch * 32 + lk * 8;
            f16x8 vfrag = *reinterpret_cast<const f16x8*>(vp);
            pv[d0] = __builtin_amdgcn_mfma_f32_16x16x32_f16(vfrag, pf.v, pv[d0], 0, 0, 0);
        }
    }

    // ---- split-K reduce: pv[d0][e] = O^T[dim=d0*16+lk*4+e][qrow=lm] ----
    #pragma unroll
    for (int d0 = 0; d0 < 4; ++d0)
        #pragma unroll
        for (int e = 0; e < 4; ++e)
            s_red[w][lm][d0 * 16 + lk * 4 + e] = pv[d0][e];
    __syncthreads();

    #pragma unroll
    for (int rep = 0; rep < 2; ++rep) {
        const int idx = t + rep * 512;
        const int qr  = idx >> 6;
        const int d   = idx & 63;
        float o = 0.f;
        #pragma unroll
        for (int ww = 0; ww < NWAVES; ++ww) o += s_red[ww][qr][d];
        Of[(size_t)(row0 + qr) * DHEAD + d] = o * 0.125f;
    }
}

extern "C" void kernel_launch(void* const* d_in, const int* in_sizes, int n_in,
                              void* d_out, int out_size, void* d_ws, size_t ws_size,
                              hipStream_t stream) {
    const float* q = (const float*)d_in[0];
    const float* k = (const float*)d_in[1];
    const float* v = (const float*)d_in[2];
    float* out = (float*)d_out;

    const int nElem = in_sizes[0];                    // B*H*S*D
    const int BH    = nElem / (S_LEN * DHEAD);

    unsigned short* kh = (unsigned short*)d_ws;
    unsigned short* vt = kh + nElem;

    const int n8 = nElem / 8;
    cvt_f16_kernel<<<(n8 + 255) / 256, 256, 0, stream>>>(k, (uint4*)kh, n8);
    vt_kernel<<<BH * (S_LEN / 64), 256, 0, stream>>>(v, vt);
    spx_main<<<BH * (S_LEN / BROWS), 512, 0, stream>>>(q, kh, vt, out);
}